// Round 1
// baseline (135.953 us; speedup 1.0000x reference)
//
#include <hip/hip_runtime.h>

#define BATCH 50
#define NATOMS 512
#define NBONDS 4096

__device__ __forceinline__ float sigmoidf_(float x){ return 1.f/(1.f+__expf(-x)); }

// exact transcription of reference _taper
__device__ __forceinline__ float taperf_(float r, float rmin, float rmax){
    float r3  = (r > rmax) ? 1.f : 0.f;
    bool  ok  = (r <= rmax) && (r > rmin);
    float r2  = ok ? r   : 0.f;
    float r20 = ok ? 1.f : 0.f;
    float d   = rmin - rmax;
    float rterm = 1.f/(d*d*d);
    float rm  = rmin*r20;
    float rd  = rm - r2;
    float trm1 = rm + 2.f*r2 - 3.f*rmax*r20;
    return rterm*rd*rd*trm1 + r3;
}

// claim ownership of each (i,j) pair: lowest bond index wins.
// duplicates carry identical bop values ('.set' semantics => count once).
__global__ __launch_bounds__(256) void claim_kernel(const int* __restrict__ bdid,
                                                    unsigned* __restrict__ table){
    int k = blockIdx.x*256 + threadIdx.x;
    if(k < NBONDS){
        int i = bdid[2*k], j = bdid[2*k+1];
        atomicMin(&table[i*NATOMS + j], (unsigned)k);
    }
}

__global__ __launch_bounds__(256) void bond_kernel(
    const float* __restrict__ x, const float* __restrict__ cell, const float* __restrict__ rcell,
    const float* __restrict__ gp, const float* __restrict__ bp,
    const float* __restrict__ fe_wi, const float* __restrict__ fe_w, const float* __restrict__ fe_b,
    const float* __restrict__ fe_wo, const float* __restrict__ fe_bo,
    const int* __restrict__ bdid, const unsigned* __restrict__ table,
    float* __restrict__ Delta, float* __restrict__ Delta_pi, float* __restrict__ SO,
    float* __restrict__ out)
{
    __shared__ float s_wi[24], s_w[320], s_bb[40], s_wo[8];
    __shared__ float s_cell[9], s_rcell[9];
    __shared__ float s_red[256];
    int tid = threadIdx.x;
    int b   = blockIdx.y;

    for(int t=tid;t<24;t+=256)  s_wi[t]=fe_wi[t];
    for(int t=tid;t<320;t+=256) s_w[t]=fe_w[t];
    for(int t=tid;t<40;t+=256)  s_bb[t]=fe_b[t];
    for(int t=tid;t<8;t+=256)   s_wo[t]=fe_wo[t];
    if(tid<9){ s_cell[tid]=cell[b*9+tid]; s_rcell[tid]=rcell[b*9+tid]; }
    __syncthreads();

    float botol = gp[6];
    float rosi=bp[0], ropi=bp[1], ropp=bp[2];
    float bo1=bp[3], bo2=bp[4], bo3=bp[5], bo4=bp[6], bo5=bp[7], bo6=bp[8], Desi=bp[9];
    float bo_out = fe_bo[0];

    int k = blockIdx.x*256 + tid;           // NBONDS == grid.x*256 exactly
    int i = bdid[2*k], j = bdid[2*k+1];
    const float* xb = x + (size_t)b*(NATOMS*3);
    float dx0 = xb[3*i+0]-xb[3*j+0];
    float dx1 = xb[3*i+1]-xb[3*j+1];
    float dx2 = xb[3*i+2]-xb[3*j+2];
    // fractional coords, minimum image, back to cartesian
    float f0 = dx0*s_rcell[0]+dx1*s_rcell[3]+dx2*s_rcell[6];
    float f1 = dx0*s_rcell[1]+dx1*s_rcell[4]+dx2*s_rcell[7];
    float f2 = dx0*s_rcell[2]+dx1*s_rcell[5]+dx2*s_rcell[8];
    f0 = (f0>0.5f)?f0-1.f:f0; f0 = (f0<-0.5f)?f0+1.f:f0;
    f1 = (f1>0.5f)?f1-1.f:f1; f1 = (f1<-0.5f)?f1+1.f:f1;
    f2 = (f2>0.5f)?f2-1.f:f2; f2 = (f2<-0.5f)?f2+1.f:f2;
    float v0 = f0*s_cell[0]+f1*s_cell[3]+f2*s_cell[6];
    float v1 = f0*s_cell[1]+f1*s_cell[4]+f2*s_cell[7];
    float v2 = f0*s_cell[2]+f1*s_cell[5]+f2*s_cell[8];
    float r = sqrtf(v0*v0+v1*v1+v2*v2);

    float eterm1 = (1.f+botol)*__expf(bo1*__powf(r/rosi, bo2));
    float eterm2 = __expf(bo3*__powf(r/ropi, bo4));
    float eterm3 = __expf(bo5*__powf(r/ropp, bo6));
    float tmax = 2.f*botol;
    float si = taperf_(eterm1, botol, tmax)*(eterm1-botol);
    float pi = taperf_(eterm2, botol, tmax)*eterm2;
    float pp = taperf_(eterm3, botol, tmax)*eterm3;

    // ---- MLP: 3 -> 8 -> (8x8)x5 -> 1, sigmoid everywhere ----
    float o[8];
    #pragma unroll
    for(int u=0;u<8;u++)
        o[u] = sigmoidf_(si*s_wi[u] + pi*s_wi[8+u] + pp*s_wi[16+u]);
    #pragma unroll
    for(int l=0;l<5;l++){
        float no[8];
        #pragma unroll
        for(int u=0;u<8;u++){
            float a = s_bb[l*8+u];
            #pragma unroll
            for(int v=0;v<8;v++) a = fmaf(o[v], s_w[l*64+v*8+u], a);
            no[u] = sigmoidf_(a);
        }
        #pragma unroll
        for(int u=0;u<8;u++) o[u]=no[u];
    }
    float a = bo_out;
    #pragma unroll
    for(int v=0;v<8;v++) a = fmaf(o[v], s_wo[v], a);
    float esi = sigmoidf_(a);

    // per-atom scatter (unique pairs only)
    if(table[i*NATOMS+j] == (unsigned)k){
        float bop = si+pi+pp;
        float dpi = pi+pp;
        float* Db = Delta    + (size_t)b*NATOMS;
        float* Pb = Delta_pi + (size_t)b*NATOMS;
        float* Sb = SO       + (size_t)b*NATOMS;
        atomicAdd(&Db[i], bop); atomicAdd(&Db[j], bop);
        atomicAdd(&Pb[i], dpi); atomicAdd(&Pb[j], dpi);
        atomicAdd(&Sb[i], si);  atomicAdd(&Sb[j], si);
    }

    // ebond: sum over ALL bonds (duplicates included)
    s_red[tid] = -Desi*esi;
    __syncthreads();
    for(int s=128;s>0;s>>=1){
        if(tid<s) s_red[tid]+=s_red[tid+s];
        __syncthreads();
    }
    if(tid==0) atomicAdd(&out[b], s_red[0]);
}

__global__ __launch_bounds__(256) void atom_kernel(
    const float* __restrict__ sp_p, const float* __restrict__ gp, const int* __restrict__ spec,
    const float* __restrict__ Delta, const float* __restrict__ Delta_pi, const float* __restrict__ SO,
    float* __restrict__ out)
{
    __shared__ float s_red[256];
    int tid = threadIdx.x;
    int n = blockIdx.x*256 + tid;
    int b = blockIdx.y;
    float lp1=gp[0], ovun3=gp[1], ovun4=gp[2], ovun6=gp[3], ovun7=gp[4], ovun8=gp[5];
    int s = spec[n];
    float val  = sp_p[s*5+0], vale = sp_p[s*5+1], lp2 = sp_p[s*5+2];
    float ovun2= sp_p[s*5+3], ovun5= sp_p[s*5+4];
    size_t idx = (size_t)b*NATOMS + n;
    float D = Delta[idx], Dpi = Delta_pi[idx], so = SO[idx];

    float Nlp = 0.5f*(vale-val);
    float de  = 0.5f*(D-vale);
    float De  = fminf(ceilf(de), 0.f);          // -relu(-ceil(x)) == min(ceil(x),0)
    float t   = 1.f + de - De;
    float nlp = -De + __expf(-lp1*4.f*t*t);
    float Dlp = fmaxf(Nlp - nlp + 1.f, 0.f) - 1.f;
    float Elone = lp2*Dlp/(1.f+__expf(-75.f*Dlp));
    float dlp = D - val - Dlp/(1.f + ovun3*__expf(ovun4*Dpi));
    float denom = dlp + val;
    float otrm1 = 1.f/((denom!=0.f)?denom:1e-8f);
    float Eover = so*otrm1*dlp*sigmoidf_(-ovun2*dlp);
    float Eunder = -ovun5*(1.f-__expf(ovun6*dlp))*sigmoidf_(ovun2*dlp)
                   /(1.f + ovun7*__expf(ovun8*Dpi));

    s_red[tid] = Elone + Eover + Eunder;
    __syncthreads();
    for(int st=128; st>0; st>>=1){
        if(tid<st) s_red[tid]+=s_red[tid+st];
        __syncthreads();
    }
    if(tid==0) atomicAdd(&out[b], s_red[0]);
}

extern "C" void kernel_launch(void* const* d_in, const int* in_sizes, int n_in,
                              void* d_out, int out_size, void* d_ws, size_t ws_size,
                              hipStream_t stream)
{
    const float* x     = (const float*)d_in[0];
    const float* cell  = (const float*)d_in[1];
    const float* rcell = (const float*)d_in[2];
    const float* sp_p  = (const float*)d_in[3];
    const float* gp    = (const float*)d_in[4];
    const float* bp    = (const float*)d_in[5];
    const float* fe_wi = (const float*)d_in[6];
    const float* fe_w  = (const float*)d_in[7];
    const float* fe_b  = (const float*)d_in[8];
    const float* fe_wo = (const float*)d_in[9];
    const float* fe_bo = (const float*)d_in[10];
    const int*   bdid  = (const int*)d_in[11];
    const int*   spec  = (const int*)d_in[12];
    float* out = (float*)d_out;

    // ws layout: Delta | Delta_pi | SO | claim table
    float* Delta    = (float*)d_ws;
    float* Delta_pi = Delta + BATCH*NATOMS;
    float* SO       = Delta_pi + BATCH*NATOMS;
    unsigned* table = (unsigned*)(SO + BATCH*NATOMS);   // NATOMS*NATOMS uints (1 MiB)

    hipMemsetAsync(out, 0, BATCH*sizeof(float), stream);
    hipMemsetAsync(Delta, 0, (size_t)3*BATCH*NATOMS*sizeof(float), stream);
    hipMemsetAsync(table, 0xFF, (size_t)NATOMS*NATOMS*sizeof(unsigned), stream);

    claim_kernel<<<dim3(NBONDS/256), 256, 0, stream>>>(bdid, table);
    bond_kernel<<<dim3(NBONDS/256, BATCH), 256, 0, stream>>>(
        x, cell, rcell, gp, bp, fe_wi, fe_w, fe_b, fe_wo, fe_bo, bdid, table,
        Delta, Delta_pi, SO, out);
    atom_kernel<<<dim3(NATOMS/256, BATCH), 256, 0, stream>>>(
        sp_p, gp, spec, Delta, Delta_pi, SO, out);
}